// Round 1
// baseline (82247.772 us; speedup 1.0000x reference)
//
#include <hip/hip_runtime.h>
#include <hip/hip_bf16.h>

// Problem: hypernetwork RNN scan. B=16, N=2048, M=H=64, L*E=1024, Cout=256.
// Round 0 baseline:
//   K1: swizzle W_dec_w -> bf16 thread-contiguous layout; dec_w -> bf16
//   K2: T[l,v,h2] = emb[v,:] @ {W_enc_w|b_enc_w}[64+16l : 64+16l+16, :]  (8 MB)
//   K3: P[t,b,h2] = bias[h2] + sum_l T[l, tok(b,t+l), h2]               (16 MB)
//   K4: sequential recurrence, 16 WGs (one per batch), Wd streamed from L2
//       in bf16, fp32 accumulation. Measures per-CU L2 stream BW for the
//       Round-1 decision (register-resident Wd + MFMA + multi-WG barrier).

typedef unsigned int uint_t;
typedef unsigned short us_t;

__device__ __forceinline__ us_t f2bf(float f) {
    uint_t u = __float_as_uint(f);
    uint_t r = u + 0x7fffu + ((u >> 16) & 1u);   // RNE
    return (us_t)(r >> 16);
}
__device__ __forceinline__ float bf2f(us_t s) {
    return __uint_as_float(((uint_t)s) << 16);
}
__device__ __forceinline__ float bflo(uint_t u) { return __uint_as_float(u << 16); }
__device__ __forceinline__ float bfhi(uint_t u) { return __uint_as_float(u & 0xffff0000u); }

// ---------------- K1: convert/swizzle weights ----------------
// WdX layout: WdX[((c*8+l)*512 + lane)*8 + k] = Wd[h, i*64 + j]
//   with p = c*512+lane (row index, p = h*64+i), j = l*8+k.
// => in K4, thread `tid` loads uint4 at index ((c*8+l)*512 + tid): 16 B/lane,
//    perfectly coalesced, row-private (no cross-lane reduction).
__global__ void cvt_kernel(const float* __restrict__ Wdecw,
                           const float* __restrict__ decw,
                           us_t* __restrict__ WdX, us_t* __restrict__ decwb) {
    int o = blockIdx.x * 256 + threadIdx.x;
    if (o < 262144) {
        int k = o & 7;
        int lane = (o >> 3) & 511;
        int l = (o >> 12) & 7;
        int c = o >> 15;
        int p = c * 512 + lane;      // row = h*64 + i
        int h = p >> 6, i = p & 63;
        int j = l * 8 + k;
        WdX[o] = f2bf(Wdecw[h * 4096 + i * 64 + j]);
    } else {
        int oo = o - 262144;
        if (oo < 16384) decwb[oo] = f2bf(decw[oo]);
    }
}

// ---------------- K2: token contribution table ----------------
__global__ void build_T(const float* __restrict__ emb, const float* __restrict__ Wencw,
                        const float* __restrict__ bencw, float* __restrict__ T) {
    int l = blockIdx.x >> 8, v = blockIdx.x & 255, h2 = threadIdx.x;  // h2 < 128
    float acc = 0.f;
#pragma unroll
    for (int e = 0; e < 16; ++e) {
        int d = 64 + l * 16 + e;  // row of the 1088-row encoder weight
        float w = (h2 < 64) ? Wencw[d * 64 + h2] : bencw[d * 64 + (h2 - 64)];
        acc += emb[v * 16 + e] * w;
    }
    T[blockIdx.x * 128 + h2] = acc;
}

// ---------------- K3: window precompute P ----------------
__global__ void build_P(const float* __restrict__ T, const int* __restrict__ x0,
                        const float* __restrict__ Wencb, const float* __restrict__ bencb,
                        float* __restrict__ P) {
    int t = blockIdx.x >> 4, b = blockIdx.x & 15, h2 = threadIdx.x;  // h2 < 128
    float acc = (h2 < 64) ? Wencb[h2] : bencb[h2 - 64];
    for (int l = 0; l < 64; ++l) {
        int p = t + l;
        int v = (p < 64) ? 0 : x0[b * 2048 + (p - 64)];  // left-pad with token 0
        acc += T[(l * 256 + v) * 128 + h2];
    }
    P[blockIdx.x * 128 + h2] = acc;  // blockIdx.x == t*16+b
}

// ---------------- K4: sequential recurrence ----------------
// One workgroup per batch element; 512 threads (8 waves).
// LDS ~51 KB (under the 64 KB static limit).
__global__ __launch_bounds__(512) void recur(
    const int* __restrict__ x0, const float* __restrict__ Wencw,
    const float* __restrict__ bencw, const float* __restrict__ bdecw,
    const float* __restrict__ bdecb, const float* __restrict__ Wdecb,
    const float* __restrict__ decb, const us_t* __restrict__ WdX,
    const us_t* __restrict__ decwb, const float* __restrict__ P,
    float* __restrict__ out) {
    const int b = blockIdx.x;
    const int tid = threadIdx.x;

    __shared__ float m_s[64], nm_s[64], hw_s[64], hb_s[64], logit_s[256];
    __shared__ float V_s[4096];          // V[h*64+i] = sum_j Wd[h,i*64+j]*m[j]
    __shared__ us_t EWm_s[8192];         // [j<64][h2<128]: m-part of both encoders (bf16)
    __shared__ us_t bdec_s[4096];        // b_dec_w [h][i] (bf16)
    __shared__ us_t wdbt_s[4096];        // W_dec_b transposed: [j][i] = Wdecb[i*64+j] (bf16)

    for (int k = tid; k < 8192; k += 512) {
        int j = k >> 7, h2 = k & 127;
        float v = (h2 < 64) ? Wencw[j * 64 + h2] : bencw[j * 64 + (h2 - 64)];
        EWm_s[k] = f2bf(v);
    }
    for (int k = tid; k < 4096; k += 512) bdec_s[k] = f2bf(bdecw[k]);
    for (int k = tid; k < 4096; k += 512) {
        int j = k >> 6, i = k & 63;
        wdbt_s[k] = f2bf(Wdecb[i * 64 + j]);
    }
    if (tid < 64) m_s[tid] = 0.f;
    __syncthreads();

    const uint4* Wd4 = (const uint4*)WdX;

    for (int t = 0; t < 2048; ++t) {
        // preload m into registers (broadcast LDS reads, fully unrolled)
        float mreg[64];
#pragma unroll
        for (int j = 0; j < 64; ++j) mreg[j] = m_s[j];

        // (b) V[h,i]: each thread owns 8 full rows (p = c*512+tid), coalesced
        // 16 B/lane bf16 loads from the swizzled WdX. 262K MACs total.
#pragma unroll
        for (int c = 0; c < 8; ++c) {
            float acc = 0.f;
#pragma unroll
            for (int l = 0; l < 8; ++l) {
                uint4 q = Wd4[(c * 8 + l) * 512 + tid];
                acc += bflo(q.x) * mreg[l * 8 + 0] + bfhi(q.x) * mreg[l * 8 + 1]
                     + bflo(q.y) * mreg[l * 8 + 2] + bfhi(q.y) * mreg[l * 8 + 3]
                     + bflo(q.z) * mreg[l * 8 + 4] + bfhi(q.z) * mreg[l * 8 + 5]
                     + bflo(q.w) * mreg[l * 8 + 6] + bfhi(q.w) * mreg[l * 8 + 7];
            }
            V_s[c * 512 + tid] = acc;
        }

        // (a) encoders: henc = sigmoid(P[t,b,:] + m @ EWm)   (threads 0..127)
        if (tid < 128) {
            float acc = P[(t * 16 + b) * 128 + tid];
#pragma unroll
            for (int j = 0; j < 64; ++j) acc += mreg[j] * bf2f(EWm_s[j * 128 + tid]);
            float s = 1.f / (1.f + __expf(-acc));
            if (tid < 64) hw_s[tid] = s; else hb_s[tid - 64] = s;
        }
        __syncthreads();

        // (c) r[i] = sum_h hw[h]*V[h,i] + sum_j Wdb[i,j]*m[j] + bm[i]; new m
        if (tid < 64) {
            float r = bdecb[tid];
            float rv = 0.f, cmv = 0.f;
#pragma unroll
            for (int h = 0; h < 64; ++h) {
                rv += hw_s[h] * V_s[h * 64 + tid];
                r  += hb_s[h] * bf2f(bdec_s[h * 64 + tid]);
            }
#pragma unroll
            for (int j = 0; j < 64; ++j) cmv += mreg[j] * bf2f(wdbt_s[j * 64 + tid]);
            float tot = rv + cmv + r;
            nm_s[tid] = 1.f / (1.f + __expf(-tot));
        }
        __syncthreads();

        // (d) logits (threads 0..255) + m-copy (threads 256..319, disjoint)
        if (tid < 256) {
            float lg = decb[tid];
#pragma unroll
            for (int mm = 0; mm < 64; ++mm) lg += nm_s[mm] * bf2f(decwb[mm * 256 + tid]);
            logit_s[tid] = lg;
        } else if (tid < 320) {
            m_s[tid - 256] = nm_s[tid - 256];
        }
        __syncthreads();

        // (e) log-softmax + NLL in bits (wave 0 only)
        if (tid < 64) {
            float l0 = logit_s[tid], l1 = logit_s[tid + 64];
            float l2 = logit_s[tid + 128], l3 = logit_s[tid + 192];
            float mx = fmaxf(fmaxf(l0, l1), fmaxf(l2, l3));
#pragma unroll
            for (int o = 32; o > 0; o >>= 1) mx = fmaxf(mx, __shfl_xor(mx, o, 64));
            float se = __expf(l0 - mx) + __expf(l1 - mx) + __expf(l2 - mx) + __expf(l3 - mx);
#pragma unroll
            for (int o = 32; o > 0; o >>= 1) se += __shfl_xor(se, o, 64);
            if (tid == 0) {
                int y = x0[b * 2048 + t];
                float lse = mx + __logf(se);
                out[t * 16 + b] = (lse - logit_s[y]) * 1.4426950408889634f;
            }
        }
        __syncthreads();
    }
}

extern "C" void kernel_launch(void* const* d_in, const int* in_sizes, int n_in,
                              void* d_out, int out_size, void* d_ws, size_t ws_size,
                              hipStream_t stream) {
    const int*   x0    = (const int*)d_in[0];
    const float* emb   = (const float*)d_in[1];
    const float* Wencw = (const float*)d_in[2];
    const float* Wencb = (const float*)d_in[3];
    const float* Wdecw = (const float*)d_in[4];
    const float* Wdecb = (const float*)d_in[5];
    const float* bencw = (const float*)d_in[6];
    const float* bencb = (const float*)d_in[7];
    const float* bdecw = (const float*)d_in[8];
    const float* bdecb = (const float*)d_in[9];
    const float* decw  = (const float*)d_in[10];
    const float* decb  = (const float*)d_in[11];
    float* out = (float*)d_out;

    char* ws = (char*)d_ws;
    us_t*  WdX   = (us_t*)(ws);                 // 524288 B
    us_t*  decwb = (us_t*)(ws + 524288);        // 32768 B
    float* T     = (float*)(ws + 557056);       // 8388608 B
    float* P     = (float*)(ws + 8945664);      // 16777216 B  (end ~24.5 MB)

    cvt_kernel<<<1088, 256, 0, stream>>>(Wdecw, decw, WdX, decwb);
    build_T<<<16384, 128, 0, stream>>>(emb, Wencw, bencw, T);
    build_P<<<32768, 128, 0, stream>>>(T, x0, Wencb, bencb, P);
    recur<<<16, 512, 0, stream>>>(x0, Wencw, bencw, bdecw, bdecb, Wdecb,
                                  decb, WdX, decwb, P, out);
}

// Round 2
// 18706.566 us; speedup vs baseline: 4.3967x; 4.3967x over previous
//
#include <hip/hip_runtime.h>
#include <hip/hip_bf16.h>

// Hypernetwork RNN scan. B=16, N=2048, M=H=64, L*E=1024, Cout=256.
// Round 2: LDS-resident weights + 4-WG-per-batch slice parallelism.
//   K1 cvt:    swizzle W_dec_w -> bf16 slice/LDS-linear layout; dec_w -> bf16
//   K2 build_T: T[l,v,h2] = emb[v,:] @ enc_rows(64+16l..+16)          (8 MB)
//   K3 build_P: P[t,b,h2] = bias[h2] + sum_l T[l, tok]               (16 MB)
//   K4 recur:  64 WGs = 16 batches x 4 i-slices. Wd slice (128 KB) in LDS.
//              Per step: henc (redundant) + V slice + r + sigmoid ->
//              publish 16 floats (agent release) -> counter barrier ->
//              reload full m into registers. m history -> ws.
//   K5 loss:   parallel logits + LSE + NLL over all 2048*16 rows.

typedef unsigned int uint_t;
typedef unsigned short us_t;

__device__ __forceinline__ us_t f2bf(float f) {
    uint_t u = __float_as_uint(f);
    uint_t r = u + 0x7fffu + ((u >> 16) & 1u);   // RNE
    return (us_t)(r >> 16);
}
__device__ __forceinline__ float bf2f(us_t s) {
    return __uint_as_float(((uint_t)s) << 16);
}
__device__ __forceinline__ float bflo(uint_t u) { return __uint_as_float(u << 16); }
__device__ __forceinline__ float bfhi(uint_t u) { return __uint_as_float(u & 0xffff0000u); }

#define MAC8(q, base, acc)                                              \
    acc += bflo(q.x) * mreg[(base) + 0] + bfhi(q.x) * mreg[(base) + 1]  \
         + bflo(q.y) * mreg[(base) + 2] + bfhi(q.y) * mreg[(base) + 3]  \
         + bflo(q.z) * mreg[(base) + 4] + bfhi(q.z) * mreg[(base) + 5]  \
         + bflo(q.w) * mreg[(base) + 6] + bfhi(q.w) * mreg[(base) + 7];

// ---------------- K1: convert/swizzle weights ----------------
// WdG us-layout [s<4][jp<8][o<1024][k<8], o = h*16+il, value = Wd[h][(s*16+il)*64 + jp*8+k].
// Recur WG s memcpys its 64 KB..128 KB slice LDS-linearly; phase-A reads are
// uint4 at (jp*1024 + o) -> lane-contiguous 16 B, conflict-free.
__global__ void cvt_kernel(const float* __restrict__ Wdecw,
                           const float* __restrict__ decw,
                           us_t* __restrict__ WdG, us_t* __restrict__ decwb) {
    int o = blockIdx.x * 256 + threadIdx.x;
    if (o < 262144) {
        int s = o >> 16;
        int idx = o & 65535;
        int k = idx & 7;
        int oo = (idx >> 3) & 1023;
        int jp = idx >> 13;
        int h = oo >> 4, il = oo & 15;
        int i = s * 16 + il;
        int j = jp * 8 + k;
        WdG[o] = f2bf(Wdecw[h * 4096 + i * 64 + j]);
    } else {
        int oo = o - 262144;
        if (oo < 16384) decwb[oo] = f2bf(decw[oo]);
    }
}

// ---------------- K2: token contribution table ----------------
__global__ void build_T(const float* __restrict__ emb, const float* __restrict__ Wencw,
                        const float* __restrict__ bencw, float* __restrict__ T) {
    int l = blockIdx.x >> 8, v = blockIdx.x & 255, h2 = threadIdx.x;  // h2 < 128
    float acc = 0.f;
#pragma unroll
    for (int e = 0; e < 16; ++e) {
        int d = 64 + l * 16 + e;
        float w = (h2 < 64) ? Wencw[d * 64 + h2] : bencw[d * 64 + (h2 - 64)];
        acc += emb[v * 16 + e] * w;
    }
    T[blockIdx.x * 128 + h2] = acc;
}

// ---------------- K3: window precompute P ----------------
__global__ void build_P(const float* __restrict__ T, const int* __restrict__ x0,
                        const float* __restrict__ Wencb, const float* __restrict__ bencb,
                        float* __restrict__ P) {
    int t = blockIdx.x >> 4, b = blockIdx.x & 15, h2 = threadIdx.x;  // h2 < 128
    float acc = (h2 < 64) ? Wencb[h2] : bencb[h2 - 64];
    for (int l = 0; l < 64; ++l) {
        int p = t + l;
        int v = (p < 64) ? 0 : x0[b * 2048 + (p - 64)];
        acc += T[(l * 256 + v) * 128 + h2];
    }
    P[blockIdx.x * 128 + h2] = acc;
}

// ---------------- K4: sequential recurrence ----------------
// grid 64: b = blk&15, s = blk>>4 (slices of a batch land on the same XCD
// under the usual %8 round-robin -- locality heuristic only).
__global__ __launch_bounds__(512) void recur(
    const float* __restrict__ Wencw, const float* __restrict__ bencw,
    const float* __restrict__ bdecw, const float* __restrict__ bdecb,
    const float* __restrict__ Wdecb, const us_t* __restrict__ WdG,
    const float* __restrict__ P, float* __restrict__ mh,
    unsigned* __restrict__ ctr) {
    const int blk = blockIdx.x;
    const int b = blk & 15, s = blk >> 4;
    const int tid = threadIdx.x;

    extern __shared__ char smem[];
    us_t*  Wd_lds = (us_t*)smem;                  // 131072 B
    us_t*  EWm2   = (us_t*)(smem + 131072);       // 16384 B [jp][h2][8]
    us_t*  wdbt_s = (us_t*)(smem + 147456);       // 2048 B  [j][il]
    us_t*  bdec_s = (us_t*)(smem + 149504);       // 2048 B  [h][il]
    float* hw_s   = (float*)(smem + 151552);      // 256 B
    float* hb_s   = (float*)(smem + 151808);      // 256 B
    float* V_s    = (float*)(smem + 152064);      // 4096 B  [h*16+il]
    float* rp_s   = (float*)(smem + 156160);      // 512 B   [p<8][il]
    float* bias_s = (float*)(smem + 156672);      // 64 B
    // total 156736

    // ---- init: stage Wd slice (LDS-linear), encoder m-rows, small mats ----
    {
        const uint4* g4 = (const uint4*)WdG + s * 8192;
        uint4* l4 = (uint4*)Wd_lds;
        for (int k = tid; k < 8192; k += 512) l4[k] = g4[k];
    }
    for (int k = tid; k < 8192; k += 512) {
        int kk = k & 7, h2 = (k >> 3) & 127, jp = k >> 10;
        int j = jp * 8 + kk;
        float v = (h2 < 64) ? Wencw[j * 64 + h2] : bencw[j * 64 + (h2 - 64)];
        EWm2[k] = f2bf(v);
    }
    for (int k = tid; k < 1024; k += 512) {
        int j = k >> 4, il = k & 15;
        wdbt_s[k] = f2bf(Wdecb[(s * 16 + il) * 64 + j]);   // W_dec_b[i*64+j]
        bdec_s[k] = f2bf(bdecw[j * 64 + s * 16 + il]);     // b_dec_w[h][i], j plays h
    }
    if (tid < 16) bias_s[tid] = bdecb[s * 16 + tid];
    __syncthreads();

    float mreg[64];
#pragma unroll
    for (int j = 0; j < 64; ++j) mreg[j] = 0.f;

    float preg = 0.f;
    if (tid < 128) preg = P[b * 128 + tid];  // t = 0

    const uint4* Wd4 = (const uint4*)Wd_lds;
    const uint4* EW4 = (const uint4*)EWm2;

    for (int t = 0; t < 2048; ++t) {
        // ---- phase A: prefetch P(t+1), V slice, henc ----
        float pnext = 0.f;
        int tp = (t < 2047) ? (t + 1) : 2047;
        if (tid < 128) pnext = P[(tp * 16 + b) * 128 + tid];

        float a0 = 0.f, a1 = 0.f;
#pragma unroll
        for (int jp = 0; jp < 8; ++jp) {
            uint4 q0 = Wd4[jp * 1024 + tid];
            uint4 q1 = Wd4[jp * 1024 + tid + 512];
            MAC8(q0, jp * 8, a0);
            MAC8(q1, jp * 8, a1);
        }
        V_s[tid] = a0;
        V_s[tid + 512] = a1;

        if (tid < 128) {
            float acc = preg;
#pragma unroll
            for (int jp = 0; jp < 8; ++jp) {
                uint4 e = EW4[jp * 128 + tid];
                MAC8(e, jp * 8, acc);
            }
            float sg = 1.f / (1.f + __expf(-acc));
            if (tid < 64) hw_s[tid] = sg; else hb_s[tid - 64] = sg;
        }
        preg = pnext;
        __syncthreads();

        // ---- phase B: r partials ----
        if (tid < 128) {
            int il = tid & 15, q = (tid >> 4) & 3;
            if (tid < 64) {
                float r = 0.f;
#pragma unroll
                for (int hh = 0; hh < 16; ++hh) {
                    int h = q * 16 + hh;
                    r += hw_s[h] * V_s[h * 16 + il];
                }
                rp_s[q * 16 + il] = r;
            } else {
                float r = 0.f;
#pragma unroll
                for (int kk = 0; kk < 16; ++kk) {
                    int jh = q * 16 + kk;
                    r += mreg[jh] * bf2f(wdbt_s[jh * 16 + il]);
                    r += hb_s[jh] * bf2f(bdec_s[jh * 16 + il]);
                }
                rp_s[64 + q * 16 + il] = r;
            }
        }
        __syncthreads();

        // ---- phase C: finalize m slice, publish (agent-scope release) ----
        if (tid < 16) {
            float r = bias_s[tid];
#pragma unroll
            for (int p = 0; p < 8; ++p) r += rp_s[p * 16 + tid];
            float nm = 1.f / (1.f + __expf(-r));
            __hip_atomic_store(&mh[(t * 16 + b) * 64 + s * 16 + tid], nm,
                               __ATOMIC_RELEASE, __HIP_MEMORY_SCOPE_AGENT);
        }
        __syncthreads();  // drains the release stores (vmcnt) before the add

        if (tid == 0) {
            __hip_atomic_fetch_add(&ctr[b], 1u, __ATOMIC_ACQ_REL,
                                   __HIP_MEMORY_SCOPE_AGENT);
            unsigned tgt = 4u * (unsigned)(t + 1);
            while (__hip_atomic_load(&ctr[b], __ATOMIC_ACQUIRE,
                                     __HIP_MEMORY_SCOPE_AGENT) < tgt)
                __builtin_amdgcn_s_sleep(2);
            __threadfence();  // agent acquire: invalidate L1(CU)/L2(XCD) stale lines
        }
        __syncthreads();

        // ---- reload full m into registers (uniform-address float4 loads) ----
        {
            const float4* mg = (const float4*)(mh + (t * 16 + b) * 64);
#pragma unroll
            for (int p = 0; p < 16; ++p) {
                float4 v = mg[p];
                mreg[p * 4 + 0] = v.x;
                mreg[p * 4 + 1] = v.y;
                mreg[p * 4 + 2] = v.z;
                mreg[p * 4 + 3] = v.w;
            }
        }
    }
}

// ---------------- K5: parallel loss ----------------
// 1024 WGs x 256 threads; wave w handles rows wg*32 + w*8 + (0..7).
__global__ __launch_bounds__(256) void loss_kernel(
    const float* __restrict__ mh, const us_t* __restrict__ decwb,
    const float* __restrict__ decb, const int* __restrict__ x0,
    float* __restrict__ out) {
    __shared__ us_t dw[16384];
    const int tid = threadIdx.x;
    {
        const uint4* g4 = (const uint4*)decwb;
        uint4* l4 = (uint4*)dw;
        for (int k = tid; k < 2048; k += 256) l4[k] = g4[k];
    }
    __syncthreads();
    const int lane = tid & 63, wv = tid >> 6;
    float b0 = decb[lane], b1 = decb[lane + 64];
    float b2 = decb[lane + 128], b3 = decb[lane + 192];
    for (int r = 0; r < 8; ++r) {
        int row = blockIdx.x * 32 + wv * 8 + r;
        float mL = mh[row * 64 + lane];
        float l0 = b0, l1 = b1, l2 = b2, l3 = b3;
#pragma unroll
        for (int mm = 0; mm < 64; ++mm) {
            float mv = __shfl(mL, mm, 64);
            l0 += mv * bf2f(dw[mm * 256 + lane]);
            l1 += mv * bf2f(dw[mm * 256 + lane + 64]);
            l2 += mv * bf2f(dw[mm * 256 + lane + 128]);
            l3 += mv * bf2f(dw[mm * 256 + lane + 192]);
        }
        float mx = fmaxf(fmaxf(l0, l1), fmaxf(l2, l3));
#pragma unroll
        for (int o = 32; o > 0; o >>= 1) mx = fmaxf(mx, __shfl_xor(mx, o, 64));
        float se = __expf(l0 - mx) + __expf(l1 - mx) + __expf(l2 - mx) + __expf(l3 - mx);
#pragma unroll
        for (int o = 32; o > 0; o >>= 1) se += __shfl_xor(se, o, 64);
        float lse = mx + __logf(se);
        int t = row >> 4, bb = row & 15;
        int y = x0[bb * 2048 + t];
        int hi = y >> 6;
        float cand = hi == 0 ? l0 : (hi == 1 ? l1 : (hi == 2 ? l2 : l3));
        float ly = __shfl(cand, y & 63, 64);
        if (lane == 0) out[row] = (lse - ly) * 1.4426950408889634f;
    }
}

extern "C" void kernel_launch(void* const* d_in, const int* in_sizes, int n_in,
                              void* d_out, int out_size, void* d_ws, size_t ws_size,
                              hipStream_t stream) {
    const int*   x0    = (const int*)d_in[0];
    const float* emb   = (const float*)d_in[1];
    const float* Wencw = (const float*)d_in[2];
    const float* Wencb = (const float*)d_in[3];
    const float* Wdecw = (const float*)d_in[4];
    const float* Wdecb = (const float*)d_in[5];
    const float* bencw = (const float*)d_in[6];
    const float* bencb = (const float*)d_in[7];
    const float* bdecw = (const float*)d_in[8];
    const float* bdecb = (const float*)d_in[9];
    const float* decw  = (const float*)d_in[10];
    const float* decb  = (const float*)d_in[11];
    float* out = (float*)d_out;

    char* ws = (char*)d_ws;
    us_t*     WdG   = (us_t*)(ws);                    //       0 .. 524288
    us_t*     decwb = (us_t*)(ws + 524288);           //  524288 .. 557056
    unsigned* ctr   = (unsigned*)(ws + 557056);       //  557056 .. 557120 (16 u32)
    float*    T     = (float*)(ws + 557120);          //  557120 .. 8945728 (8 MB)
    float*    mh    = T;                              //  alias: T dead after build_P
    float*    P     = (float*)(ws + 8945728);         // 8945728 .. 25722944 (16 MB)

    static const int kRecurLds = 156736;
    hipFuncSetAttribute((const void*)recur,
                        hipFuncAttributeMaxDynamicSharedMemorySize, kRecurLds);

    hipMemsetAsync(ctr, 0, 64, stream);
    cvt_kernel<<<1088, 256, 0, stream>>>(Wdecw, decw, WdG, decwb);
    build_T<<<16384, 128, 0, stream>>>(emb, Wencw, bencw, T);
    build_P<<<32768, 128, 0, stream>>>(T, x0, Wencb, bencb, P);
    recur<<<64, 512, kRecurLds, stream>>>(Wencw, bencw, bdecw, bdecb, Wdecb,
                                          WdG, P, mh, ctr);
    loss_kernel<<<1024, 256, 0, stream>>>(mh, decwb, decb, x0, out);
}

// Round 3
// 14114.372 us; speedup vs baseline: 5.8272x; 1.3254x over previous
//
#include <hip/hip_runtime.h>
#include <hip/hip_bf16.h>

// Hypernetwork RNN scan. B=16, N=2048, M=H=64, L*E=1024, Cout=256.
// Round 3: relaxed-atomic flag barrier (no L2-invalidating acquire/fence in
// the steady state), wave0-only m exchange + LDS broadcast, LDS padding.
//   K1 cvt:    Wd -> bf16 slice layout; dec_w -> bf16 lane-packed (loss)
//   K2 build_T, K3 build_P: unchanged precompute (8 MB + 16 MB)
//   K4 recur:  64 WGs = 16 batches x 4 i-slices, Wd slice (128 KB) in LDS.
//   K5 loss:   parallel logits/LSE/NLL, ds_read_b64 weight reads.

typedef unsigned int uint_t;
typedef unsigned short us_t;

__device__ __forceinline__ us_t f2bf(float f) {
    uint_t u = __float_as_uint(f);
    uint_t r = u + 0x7fffu + ((u >> 16) & 1u);   // RNE
    return (us_t)(r >> 16);
}
__device__ __forceinline__ float bf2f(us_t s) {
    return __uint_as_float(((uint_t)s) << 16);
}
__device__ __forceinline__ float bflo(uint_t u) { return __uint_as_float(u << 16); }
__device__ __forceinline__ float bfhi(uint_t u) { return __uint_as_float(u & 0xffff0000u); }

#define MAC8(q, base, acc)                                              \
    acc += bflo(q.x) * mreg[(base) + 0] + bfhi(q.x) * mreg[(base) + 1]  \
         + bflo(q.y) * mreg[(base) + 2] + bfhi(q.y) * mreg[(base) + 3]  \
         + bflo(q.z) * mreg[(base) + 4] + bfhi(q.z) * mreg[(base) + 5]  \
         + bflo(q.w) * mreg[(base) + 6] + bfhi(q.w) * mreg[(base) + 7];

// ---------------- K1: convert/swizzle weights ----------------
// WdG us-layout [s<4][jp<8][o<1024][k<8], o = h*16+il,
//   value = Wd[h][(s*16+il)*64 + jp*8+k]  (uint4 at jp*1024+o is lane-contig).
// decwY us-layout [mm<64][lane<64][k<4], value = decw[mm*256 + k*64 + lane]
//   (loss lane reads ds_read_b64 -> its 4 logit columns for row mm).
__global__ void cvt_kernel(const float* __restrict__ Wdecw,
                           const float* __restrict__ decw,
                           us_t* __restrict__ WdG, us_t* __restrict__ decwY) {
    int o = blockIdx.x * 256 + threadIdx.x;
    if (o < 262144) {
        int s = o >> 16;
        int idx = o & 65535;
        int k = idx & 7;
        int oo = (idx >> 3) & 1023;
        int jp = idx >> 13;
        int h = oo >> 4, il = oo & 15;
        int i = s * 16 + il;
        int j = jp * 8 + k;
        WdG[o] = f2bf(Wdecw[h * 4096 + i * 64 + j]);
    } else {
        int oo = o - 262144;
        if (oo < 16384) {
            int k = oo & 3, lane = (oo >> 2) & 63, mm = oo >> 8;
            decwY[oo] = f2bf(decw[mm * 256 + k * 64 + lane]);
        }
    }
}

// ---------------- K2: token contribution table ----------------
__global__ void build_T(const float* __restrict__ emb, const float* __restrict__ Wencw,
                        const float* __restrict__ bencw, float* __restrict__ T) {
    int l = blockIdx.x >> 8, v = blockIdx.x & 255, h2 = threadIdx.x;  // h2 < 128
    float acc = 0.f;
#pragma unroll
    for (int e = 0; e < 16; ++e) {
        int d = 64 + l * 16 + e;
        float w = (h2 < 64) ? Wencw[d * 64 + h2] : bencw[d * 64 + (h2 - 64)];
        acc += emb[v * 16 + e] * w;
    }
    T[blockIdx.x * 128 + h2] = acc;
}

// ---------------- K3: window precompute P ----------------
__global__ void build_P(const float* __restrict__ T, const int* __restrict__ x0,
                        const float* __restrict__ Wencb, const float* __restrict__ bencb,
                        float* __restrict__ P) {
    int t = blockIdx.x >> 4, b = blockIdx.x & 15, h2 = threadIdx.x;  // h2 < 128
    float acc = (h2 < 64) ? Wencb[h2] : bencb[h2 - 64];
    for (int l = 0; l < 64; ++l) {
        int p = t + l;
        int v = (p < 64) ? 0 : x0[b * 2048 + (p - 64)];
        acc += T[(l * 256 + v) * 128 + h2];
    }
    P[blockIdx.x * 128 + h2] = acc;
}

// ---------------- K4: sequential recurrence ----------------
// grid 64: b = blk&15, s = blk>>4. ~154 KB LDS -> 1 WG/CU, all co-resident.
__global__ __launch_bounds__(512) void recur(
    const float* __restrict__ Wencw, const float* __restrict__ bencw,
    const float* __restrict__ bdecw, const float* __restrict__ bdecb,
    const float* __restrict__ Wdecb, const us_t* __restrict__ WdG,
    const float* __restrict__ P, float* __restrict__ mh,
    unsigned* __restrict__ flags) {
    const int blk = blockIdx.x;
    const int b = blk & 15, s = blk >> 4;
    const int tid = threadIdx.x;

    extern __shared__ char smem[];
    us_t*  Wd_lds = (us_t*)smem;                  // 131072 B
    us_t*  EWm2   = (us_t*)(smem + 131072);       // 16384 B [jp][h2][8]
    us_t*  wdbt_s = (us_t*)(smem + 147456);       // 2176 B  [j][il], stride 17
    us_t*  bdec_s = (us_t*)(smem + 149632);       // 2176 B  [h][il], stride 17
    float* hw_s   = (float*)(smem + 151808);      // 256 B
    float* hb_s   = (float*)(smem + 152064);      // 256 B
    float* m_s    = (float*)(smem + 152320);      // 256 B (16B-aligned)
    float* V_s    = (float*)(smem + 152576);      // 4352 B  [h][il], stride 17
    float* rp_s   = (float*)(smem + 156928);      // 512 B   [p<8][il]
    float* bias_s = (float*)(smem + 157440);      // 64 B
    // total 157504

    // ---- init ----
    {
        const uint4* g4 = (const uint4*)WdG + s * 8192;
        uint4* l4 = (uint4*)Wd_lds;
        for (int k = tid; k < 8192; k += 512) l4[k] = g4[k];
    }
    for (int k = tid; k < 8192; k += 512) {
        int kk = k & 7, h2 = (k >> 3) & 127, jp = k >> 10;
        int j = jp * 8 + kk;
        float v = (h2 < 64) ? Wencw[j * 64 + h2] : bencw[j * 64 + (h2 - 64)];
        EWm2[k] = f2bf(v);
    }
    for (int k = tid; k < 1024; k += 512) {
        int j = k >> 4, il = k & 15;
        wdbt_s[j * 17 + il] = f2bf(Wdecb[(s * 16 + il) * 64 + j]);  // W_dec_b[i][j]
        bdec_s[j * 17 + il] = f2bf(bdecw[j * 64 + s * 16 + il]);    // b_dec_w[h][i]
    }
    if (tid < 16) bias_s[tid] = bdecb[s * 16 + tid];
    __syncthreads();

    float mreg[64];
#pragma unroll
    for (int j = 0; j < 64; ++j) mreg[j] = 0.f;

    float preg = 0.f;
    if (tid < 128) preg = P[b * 128 + tid];  // t = 0

    const uint4* Wd4 = (const uint4*)Wd_lds;
    const uint4* EW4 = (const uint4*)EWm2;
    const int hA = tid >> 4, ilA = tid & 15;

    for (int t = 0; t < 2048; ++t) {
        // ---- phase A: prefetch P(t+1), V slice, henc ----
        float pnext = 0.f;
        int tp = (t < 2047) ? (t + 1) : 2047;
        if (tid < 128) pnext = P[(tp * 16 + b) * 128 + tid];

        float a0 = 0.f, a1 = 0.f;
#pragma unroll
        for (int jp = 0; jp < 8; ++jp) {
            uint4 q0 = Wd4[jp * 1024 + tid];
            uint4 q1 = Wd4[jp * 1024 + tid + 512];
            MAC8(q0, jp * 8, a0);
            MAC8(q1, jp * 8, a1);
        }
        V_s[hA * 17 + ilA] = a0;
        V_s[(hA + 32) * 17 + ilA] = a1;

        if (tid < 128) {
            float acc = preg;
#pragma unroll
            for (int jp = 0; jp < 8; ++jp) {
                uint4 e = EW4[jp * 128 + tid];
                MAC8(e, jp * 8, acc);
            }
            float sg = 1.f / (1.f + __expf(-acc));
            if (tid < 64) hw_s[tid] = sg; else hb_s[tid - 64] = sg;
        }
        preg = pnext;
        __syncthreads();

        // ---- phase B: r partials ----
        if (tid < 128) {
            int il = tid & 15, q = (tid >> 4) & 3;
            if (tid < 64) {
                float r = 0.f;
#pragma unroll
                for (int hh = 0; hh < 16; ++hh) {
                    int h = q * 16 + hh;
                    r += hw_s[h] * V_s[h * 17 + il];
                }
                rp_s[q * 16 + il] = r;
            } else {
                float r = 0.f;
#pragma unroll
                for (int kk = 0; kk < 16; ++kk) {
                    int jh = q * 16 + kk;
                    r += mreg[jh] * bf2f(wdbt_s[jh * 17 + il]);
                    r += hb_s[jh] * bf2f(bdec_s[jh * 17 + il]);
                }
                rp_s[64 + q * 16 + il] = r;
            }
        }
        __syncthreads();

        // ---- phase C: finalize m slice, publish (relaxed payload,
        //      release flag; same wave => vmcnt drain orders them) ----
        if (tid < 16) {
            float r = bias_s[tid];
#pragma unroll
            for (int p = 0; p < 8; ++p) r += rp_s[p * 16 + tid];
            float nm = 1.f / (1.f + __expf(-r));
            __hip_atomic_store(&mh[(t * 16 + b) * 64 + s * 16 + tid], nm,
                               __ATOMIC_RELAXED, __HIP_MEMORY_SCOPE_AGENT);
        }
        if (tid == 0) {
            __hip_atomic_store(&flags[b * 4 + s], (unsigned)(t + 1),
                               __ATOMIC_RELEASE, __HIP_MEMORY_SCOPE_AGENT);
        }

        // ---- barrier: lane 0 spins on 4 monotonic flags (RELAXED: no
        //      cache-invalidating acquire in the loop) ----
        if (tid == 0) {
            const unsigned tgt = (unsigned)(t + 1);
            const unsigned* fb = flags + b * 4;
            for (;;) {
                unsigned f0 = __hip_atomic_load(fb + 0, __ATOMIC_RELAXED,
                                                __HIP_MEMORY_SCOPE_AGENT);
                unsigned f1 = __hip_atomic_load(fb + 1, __ATOMIC_RELAXED,
                                                __HIP_MEMORY_SCOPE_AGENT);
                unsigned f2 = __hip_atomic_load(fb + 2, __ATOMIC_RELAXED,
                                                __HIP_MEMORY_SCOPE_AGENT);
                unsigned f3 = __hip_atomic_load(fb + 3, __ATOMIC_RELAXED,
                                                __HIP_MEMORY_SCOPE_AGENT);
                if (f0 >= tgt && f1 >= tgt && f2 >= tgt && f3 >= tgt) break;
                __builtin_amdgcn_s_sleep(1);
            }
        }
        // wave 0 reconverges; payload loads are control-dependent on the spin
        if (tid < 64) {
            float v = __hip_atomic_load(&mh[(t * 16 + b) * 64 + tid],
                                        __ATOMIC_RELAXED, __HIP_MEMORY_SCOPE_AGENT);
            m_s[tid] = v;
        }
        __syncthreads();

        // ---- broadcast m from LDS into registers ----
        {
            const float4* mg = (const float4*)m_s;
#pragma unroll
            for (int p = 0; p < 16; ++p) {
                float4 v = mg[p];
                mreg[p * 4 + 0] = v.x;
                mreg[p * 4 + 1] = v.y;
                mreg[p * 4 + 2] = v.z;
                mreg[p * 4 + 3] = v.w;
            }
        }
    }
}

// ---------------- K5: parallel loss ----------------
__global__ __launch_bounds__(256) void loss_kernel(
    const float* __restrict__ mh, const us_t* __restrict__ decwY,
    const float* __restrict__ decb, const int* __restrict__ x0,
    float* __restrict__ out) {
    __shared__ us_t dw[16384];   // [mm][lane][k<4] bf16
    const int tid = threadIdx.x;
    {
        const uint4* g4 = (const uint4*)decwY;
        uint4* l4 = (uint4*)dw;
        for (int k = tid; k < 2048; k += 256) l4[k] = g4[k];
    }
    __syncthreads();
    const int lane = tid & 63, wv = tid >> 6;
    const uint2* dwu2 = (const uint2*)dw;
    float b0 = decb[lane], b1 = decb[lane + 64];
    float b2 = decb[lane + 128], b3 = decb[lane + 192];
    for (int r = 0; r < 8; ++r) {
        int row = blockIdx.x * 32 + wv * 8 + r;
        float mL = mh[row * 64 + lane];
        float l0 = b0, l1 = b1, l2 = b2, l3 = b3;
#pragma unroll
        for (int mm = 0; mm < 64; ++mm) {
            float mv = __shfl(mL, mm, 64);
            uint2 q = dwu2[mm * 64 + lane];
            l0 += mv * bflo(q.x);
            l1 += mv * bfhi(q.x);
            l2 += mv * bflo(q.y);
            l3 += mv * bfhi(q.y);
        }
        float mx = fmaxf(fmaxf(l0, l1), fmaxf(l2, l3));
#pragma unroll
        for (int o = 32; o > 0; o >>= 1) mx = fmaxf(mx, __shfl_xor(mx, o, 64));
        float se = __expf(l0 - mx) + __expf(l1 - mx) + __expf(l2 - mx) + __expf(l3 - mx);
#pragma unroll
        for (int o = 32; o > 0; o >>= 1) se += __shfl_xor(se, o, 64);
        float lse = mx + __logf(se);
        int t = row >> 4, bb = row & 15;
        int y = x0[bb * 2048 + t];
        int hi = y >> 6;
        float cand = hi == 0 ? l0 : (hi == 1 ? l1 : (hi == 2 ? l2 : l3));
        float ly = __shfl(cand, y & 63, 64);
        if (lane == 0) out[row] = (lse - ly) * 1.4426950408889634f;
    }
}

extern "C" void kernel_launch(void* const* d_in, const int* in_sizes, int n_in,
                              void* d_out, int out_size, void* d_ws, size_t ws_size,
                              hipStream_t stream) {
    const int*   x0    = (const int*)d_in[0];
    const float* emb   = (const float*)d_in[1];
    const float* Wencw = (const float*)d_in[2];
    const float* Wencb = (const float*)d_in[3];
    const float* Wdecw = (const float*)d_in[4];
    const float* Wdecb = (const float*)d_in[5];
    const float* bencw = (const float*)d_in[6];
    const float* bencb = (const float*)d_in[7];
    const float* bdecw = (const float*)d_in[8];
    const float* bdecb = (const float*)d_in[9];
    const float* decw  = (const float*)d_in[10];
    const float* decb  = (const float*)d_in[11];
    float* out = (float*)d_out;

    char* ws = (char*)d_ws;
    us_t*     WdG   = (us_t*)(ws);                    //       0 .. 524288
    us_t*     decwY = (us_t*)(ws + 524288);           //  524288 .. 557056
    unsigned* flags = (unsigned*)(ws + 557056);       //  557056 .. 557312
    float*    T     = (float*)(ws + 557312);          //  557312 .. 8945920 (8 MB)
    float*    mh    = T;                              //  alias: T dead after build_P
    float*    P     = (float*)(ws + 8945920);         // 8945920 .. 25723136 (16 MB)

    static const int kRecurLds = 157504;
    hipFuncSetAttribute((const void*)recur,
                        hipFuncAttributeMaxDynamicSharedMemorySize, kRecurLds);

    hipMemsetAsync(flags, 0, 256, stream);
    cvt_kernel<<<1088, 256, 0, stream>>>(Wdecw, decw, WdG, decwY);
    build_T<<<16384, 128, 0, stream>>>(emb, Wencw, bencw, T);
    build_P<<<32768, 128, 0, stream>>>(T, x0, Wencb, bencb, P);
    recur<<<64, 512, kRecurLds, stream>>>(Wencw, bencw, bdecw, bdecb, Wdecb,
                                          WdG, P, mh, flags);
    loss_kernel<<<1024, 256, 0, stream>>>(mh, decwY, decb, x0, out);
}

// Round 4
// 6875.320 us; speedup vs baseline: 11.9628x; 2.0529x over previous
//
#include <hip/hip_runtime.h>
#include <hip/hip_bf16.h>

// Hypernetwork RNN scan. B=16, N=2048, M=H=64, L*E=1024, Cout=256.
// Round 4: fix the Round-2/3 catastrophe — mreg[64] was demoted to scratch
// by phase B's runtime-indexed read (mreg[jh], jh from tid), generating
// 17.2 GB/launch of private-memory write traffic (= the entire measured
// hbm_bytes). Phase B now reads m from LDS (m_s); every surviving mreg
// access is compile-time-constant, so the array stays in VGPRs.
//   K1 cvt:    Wd -> bf16 slice layout; dec_w -> bf16 lane-packed (loss)
//   K2 build_T, K3 build_P: unchanged precompute (8 MB + 16 MB)
//   K4 recur:  64 WGs = 16 batches x 4 i-slices, Wd slice (128 KB) in LDS,
//              relaxed-flag LLC barrier, wave0-only m exchange.
//   K5 loss:   parallel logits/LSE/NLL, ds_read_b64 weight reads.

typedef unsigned int uint_t;
typedef unsigned short us_t;

__device__ __forceinline__ us_t f2bf(float f) {
    uint_t u = __float_as_uint(f);
    uint_t r = u + 0x7fffu + ((u >> 16) & 1u);   // RNE
    return (us_t)(r >> 16);
}
__device__ __forceinline__ float bf2f(us_t s) {
    return __uint_as_float(((uint_t)s) << 16);
}
__device__ __forceinline__ float bflo(uint_t u) { return __uint_as_float(u << 16); }
__device__ __forceinline__ float bfhi(uint_t u) { return __uint_as_float(u & 0xffff0000u); }

#define MAC8(q, base, acc)                                              \
    acc += bflo(q.x) * mreg[(base) + 0] + bfhi(q.x) * mreg[(base) + 1]  \
         + bflo(q.y) * mreg[(base) + 2] + bfhi(q.y) * mreg[(base) + 3]  \
         + bflo(q.z) * mreg[(base) + 4] + bfhi(q.z) * mreg[(base) + 5]  \
         + bflo(q.w) * mreg[(base) + 6] + bfhi(q.w) * mreg[(base) + 7];

// ---------------- K1: convert/swizzle weights ----------------
// WdG us-layout [s<4][jp<8][o<1024][k<8], o = h*16+il,
//   value = Wd[h][(s*16+il)*64 + jp*8+k]  (uint4 at jp*1024+o is lane-contig).
// decwY us-layout [mm<64][lane<64][k<4], value = decw[mm*256 + k*64 + lane].
__global__ void cvt_kernel(const float* __restrict__ Wdecw,
                           const float* __restrict__ decw,
                           us_t* __restrict__ WdG, us_t* __restrict__ decwY) {
    int o = blockIdx.x * 256 + threadIdx.x;
    if (o < 262144) {
        int s = o >> 16;
        int idx = o & 65535;
        int k = idx & 7;
        int oo = (idx >> 3) & 1023;
        int jp = idx >> 13;
        int h = oo >> 4, il = oo & 15;
        int i = s * 16 + il;
        int j = jp * 8 + k;
        WdG[o] = f2bf(Wdecw[h * 4096 + i * 64 + j]);
    } else {
        int oo = o - 262144;
        if (oo < 16384) {
            int k = oo & 3, lane = (oo >> 2) & 63, mm = oo >> 8;
            decwY[oo] = f2bf(decw[mm * 256 + k * 64 + lane]);
        }
    }
}

// ---------------- K2: token contribution table ----------------
__global__ void build_T(const float* __restrict__ emb, const float* __restrict__ Wencw,
                        const float* __restrict__ bencw, float* __restrict__ T) {
    int l = blockIdx.x >> 8, v = blockIdx.x & 255, h2 = threadIdx.x;  // h2 < 128
    float acc = 0.f;
#pragma unroll
    for (int e = 0; e < 16; ++e) {
        int d = 64 + l * 16 + e;
        float w = (h2 < 64) ? Wencw[d * 64 + h2] : bencw[d * 64 + (h2 - 64)];
        acc += emb[v * 16 + e] * w;
    }
    T[blockIdx.x * 128 + h2] = acc;
}

// ---------------- K3: window precompute P ----------------
__global__ void build_P(const float* __restrict__ T, const int* __restrict__ x0,
                        const float* __restrict__ Wencb, const float* __restrict__ bencb,
                        float* __restrict__ P) {
    int t = blockIdx.x >> 4, b = blockIdx.x & 15, h2 = threadIdx.x;  // h2 < 128
    float acc = (h2 < 64) ? Wencb[h2] : bencb[h2 - 64];
    for (int l = 0; l < 64; ++l) {
        int p = t + l;
        int v = (p < 64) ? 0 : x0[b * 2048 + (p - 64)];
        acc += T[(l * 256 + v) * 128 + h2];
    }
    P[blockIdx.x * 128 + h2] = acc;
}

// ---------------- K4: sequential recurrence ----------------
// grid 64: b = blk&15, s = blk>>4. ~154 KB LDS -> 1 WG/CU, all co-resident.
__global__ __launch_bounds__(512) void recur(
    const float* __restrict__ Wencw, const float* __restrict__ bencw,
    const float* __restrict__ bdecw, const float* __restrict__ bdecb,
    const float* __restrict__ Wdecb, const us_t* __restrict__ WdG,
    const float* __restrict__ P, float* __restrict__ mh,
    unsigned* __restrict__ flags) {
    const int blk = blockIdx.x;
    const int b = blk & 15, s = blk >> 4;
    const int tid = threadIdx.x;

    extern __shared__ char smem[];
    us_t*  Wd_lds = (us_t*)smem;                  // 131072 B
    us_t*  EWm2   = (us_t*)(smem + 131072);       // 16384 B [jp][h2][8]
    us_t*  wdbt_s = (us_t*)(smem + 147456);       // 2176 B  [j][il], stride 17
    us_t*  bdec_s = (us_t*)(smem + 149632);       // 2176 B  [h][il], stride 17
    float* hw_s   = (float*)(smem + 151808);      // 256 B
    float* hb_s   = (float*)(smem + 152064);      // 256 B
    float* m_s    = (float*)(smem + 152320);      // 256 B (16B-aligned)
    float* V_s    = (float*)(smem + 152576);      // 4352 B  [h][il], stride 17
    float* rp_s   = (float*)(smem + 156928);      // 512 B   [p<8][il]
    float* bias_s = (float*)(smem + 157440);      // 64 B
    // total 157504

    // ---- init ----
    {
        const uint4* g4 = (const uint4*)WdG + s * 8192;
        uint4* l4 = (uint4*)Wd_lds;
        for (int k = tid; k < 8192; k += 512) l4[k] = g4[k];
    }
    for (int k = tid; k < 8192; k += 512) {
        int kk = k & 7, h2 = (k >> 3) & 127, jp = k >> 10;
        int j = jp * 8 + kk;
        float v = (h2 < 64) ? Wencw[j * 64 + h2] : bencw[j * 64 + (h2 - 64)];
        EWm2[k] = f2bf(v);
    }
    for (int k = tid; k < 1024; k += 512) {
        int j = k >> 4, il = k & 15;
        wdbt_s[j * 17 + il] = f2bf(Wdecb[(s * 16 + il) * 64 + j]);  // W_dec_b[i][j]
        bdec_s[j * 17 + il] = f2bf(bdecw[j * 64 + s * 16 + il]);    // b_dec_w[h][i]
    }
    if (tid < 16) bias_s[tid] = bdecb[s * 16 + tid];
    if (tid < 64) m_s[tid] = 0.f;
    __syncthreads();

    // mreg: compile-time-constant indexing ONLY (else the compiler demotes
    // the array to scratch -> 17 GB of private-memory traffic; see Round 3).
    float mreg[64];
#pragma unroll
    for (int j = 0; j < 64; ++j) mreg[j] = 0.f;

    float preg = 0.f;
    if (tid < 128) preg = P[b * 128 + tid];  // t = 0

    const uint4* Wd4 = (const uint4*)Wd_lds;
    const uint4* EW4 = (const uint4*)EWm2;
    const int hA = tid >> 4, ilA = tid & 15;

    for (int t = 0; t < 2048; ++t) {
        // ---- phase A: prefetch P(t+1), V slice, henc ----
        float pnext = 0.f;
        int tp = (t < 2047) ? (t + 1) : 2047;
        if (tid < 128) pnext = P[(tp * 16 + b) * 128 + tid];

        float a0 = 0.f, a1 = 0.f;
#pragma unroll
        for (int jp = 0; jp < 8; ++jp) {
            uint4 q0 = Wd4[jp * 1024 + tid];
            uint4 q1 = Wd4[jp * 1024 + tid + 512];
            MAC8(q0, jp * 8, a0);
            MAC8(q1, jp * 8, a1);
        }
        V_s[hA * 17 + ilA] = a0;
        V_s[(hA + 32) * 17 + ilA] = a1;

        if (tid < 128) {
            float acc = preg;
#pragma unroll
            for (int jp = 0; jp < 8; ++jp) {
                uint4 e = EW4[jp * 128 + tid];
                MAC8(e, jp * 8, acc);
            }
            float sg = 1.f / (1.f + __expf(-acc));
            if (tid < 64) hw_s[tid] = sg; else hb_s[tid - 64] = sg;
        }
        preg = pnext;
        __syncthreads();

        // ---- phase B: r partials (m read from LDS: runtime index is fine
        //      in LDS, fatal in a register array) ----
        if (tid < 128) {
            int il = tid & 15, q = (tid >> 4) & 3;
            if (tid < 64) {
                float r = 0.f;
#pragma unroll
                for (int hh = 0; hh < 16; ++hh) {
                    int h = q * 16 + hh;
                    r += hw_s[h] * V_s[h * 17 + il];
                }
                rp_s[q * 16 + il] = r;
            } else {
                float r = 0.f;
#pragma unroll
                for (int kk = 0; kk < 16; ++kk) {
                    int jh = q * 16 + kk;
                    r += m_s[jh] * bf2f(wdbt_s[jh * 17 + il]);
                    r += hb_s[jh] * bf2f(bdec_s[jh * 17 + il]);
                }
                rp_s[64 + q * 16 + il] = r;
            }
        }
        __syncthreads();

        // ---- phase C: finalize m slice, publish (relaxed payload,
        //      release flag; same wave => vmcnt drain orders them) ----
        if (tid < 16) {
            float r = bias_s[tid];
#pragma unroll
            for (int p = 0; p < 8; ++p) r += rp_s[p * 16 + tid];
            float nm = 1.f / (1.f + __expf(-r));
            __hip_atomic_store(&mh[(t * 16 + b) * 64 + s * 16 + tid], nm,
                               __ATOMIC_RELAXED, __HIP_MEMORY_SCOPE_AGENT);
        }
        if (tid == 0) {
            __hip_atomic_store(&flags[b * 4 + s], (unsigned)(t + 1),
                               __ATOMIC_RELEASE, __HIP_MEMORY_SCOPE_AGENT);
        }

        // ---- barrier: lane 0 spins on 4 monotonic flags (RELAXED loads:
        //      no cache-invalidating acquire in the loop) ----
        if (tid == 0) {
            const unsigned tgt = (unsigned)(t + 1);
            const unsigned* fb = flags + b * 4;
            for (;;) {
                unsigned f0 = __hip_atomic_load(fb + 0, __ATOMIC_RELAXED,
                                                __HIP_MEMORY_SCOPE_AGENT);
                unsigned f1 = __hip_atomic_load(fb + 1, __ATOMIC_RELAXED,
                                                __HIP_MEMORY_SCOPE_AGENT);
                unsigned f2 = __hip_atomic_load(fb + 2, __ATOMIC_RELAXED,
                                                __HIP_MEMORY_SCOPE_AGENT);
                unsigned f3 = __hip_atomic_load(fb + 3, __ATOMIC_RELAXED,
                                                __HIP_MEMORY_SCOPE_AGENT);
                if (f0 >= tgt && f1 >= tgt && f2 >= tgt && f3 >= tgt) break;
                __builtin_amdgcn_s_sleep(1);
            }
        }
        // wave 0 reconverges; payload loads are control-dependent on the spin
        if (tid < 64) {
            float v = __hip_atomic_load(&mh[(t * 16 + b) * 64 + tid],
                                        __ATOMIC_RELAXED, __HIP_MEMORY_SCOPE_AGENT);
            m_s[tid] = v;
        }
        __syncthreads();

        // ---- broadcast m from LDS into registers (constant indices) ----
        {
            const float4* mg = (const float4*)m_s;
#pragma unroll
            for (int p = 0; p < 16; ++p) {
                float4 v = mg[p];
                mreg[p * 4 + 0] = v.x;
                mreg[p * 4 + 1] = v.y;
                mreg[p * 4 + 2] = v.z;
                mreg[p * 4 + 3] = v.w;
            }
        }
    }
}

// ---------------- K5: parallel loss ----------------
__global__ __launch_bounds__(256) void loss_kernel(
    const float* __restrict__ mh, const us_t* __restrict__ decwY,
    const float* __restrict__ decb, const int* __restrict__ x0,
    float* __restrict__ out) {
    __shared__ us_t dw[16384];   // [mm][lane][k<4] bf16
    const int tid = threadIdx.x;
    {
        const uint4* g4 = (const uint4*)decwY;
        uint4* l4 = (uint4*)dw;
        for (int k = tid; k < 2048; k += 256) l4[k] = g4[k];
    }
    __syncthreads();
    const int lane = tid & 63, wv = tid >> 6;
    const uint2* dwu2 = (const uint2*)dw;
    float b0 = decb[lane], b1 = decb[lane + 64];
    float b2 = decb[lane + 128], b3 = decb[lane + 192];
    for (int r = 0; r < 8; ++r) {
        int row = blockIdx.x * 32 + wv * 8 + r;
        float mL = mh[row * 64 + lane];
        float l0 = b0, l1 = b1, l2 = b2, l3 = b3;
#pragma unroll
        for (int mm = 0; mm < 64; ++mm) {
            float mv = __shfl(mL, mm, 64);
            uint2 q = dwu2[mm * 64 + lane];
            l0 += mv * bflo(q.x);
            l1 += mv * bfhi(q.x);
            l2 += mv * bflo(q.y);
            l3 += mv * bfhi(q.y);
        }
        float mx = fmaxf(fmaxf(l0, l1), fmaxf(l2, l3));
#pragma unroll
        for (int o = 32; o > 0; o >>= 1) mx = fmaxf(mx, __shfl_xor(mx, o, 64));
        float se = __expf(l0 - mx) + __expf(l1 - mx) + __expf(l2 - mx) + __expf(l3 - mx);
#pragma unroll
        for (int o = 32; o > 0; o >>= 1) se += __shfl_xor(se, o, 64);
        float lse = mx + __logf(se);
        int t = row >> 4, bb = row & 15;
        int y = x0[bb * 2048 + t];
        int hi = y >> 6;
        float cand = hi == 0 ? l0 : (hi == 1 ? l1 : (hi == 2 ? l2 : l3));
        float ly = __shfl(cand, y & 63, 64);
        if (lane == 0) out[row] = (lse - ly) * 1.4426950408889634f;
    }
}

extern "C" void kernel_launch(void* const* d_in, const int* in_sizes, int n_in,
                              void* d_out, int out_size, void* d_ws, size_t ws_size,
                              hipStream_t stream) {
    const int*   x0    = (const int*)d_in[0];
    const float* emb   = (const float*)d_in[1];
    const float* Wencw = (const float*)d_in[2];
    const float* Wencb = (const float*)d_in[3];
    const float* Wdecw = (const float*)d_in[4];
    const float* Wdecb = (const float*)d_in[5];
    const float* bencw = (const float*)d_in[6];
    const float* bencb = (const float*)d_in[7];
    const float* bdecw = (const float*)d_in[8];
    const float* bdecb = (const float*)d_in[9];
    const float* decw  = (const float*)d_in[10];
    const float* decb  = (const float*)d_in[11];
    float* out = (float*)d_out;

    char* ws = (char*)d_ws;
    us_t*     WdG   = (us_t*)(ws);                    //       0 .. 524288
    us_t*     decwY = (us_t*)(ws + 524288);           //  524288 .. 557056
    unsigned* flags = (unsigned*)(ws + 557056);       //  557056 .. 557312
    float*    T     = (float*)(ws + 557312);          //  557312 .. 8945920 (8 MB)
    float*    mh    = T;                              //  alias: T dead after build_P
    float*    P     = (float*)(ws + 8945920);         // 8945920 .. 25723136 (16 MB)

    static const int kRecurLds = 157504;
    hipFuncSetAttribute((const void*)recur,
                        hipFuncAttributeMaxDynamicSharedMemorySize, kRecurLds);

    hipMemsetAsync(flags, 0, 256, stream);
    cvt_kernel<<<1088, 256, 0, stream>>>(Wdecw, decw, WdG, decwY);
    build_T<<<16384, 128, 0, stream>>>(emb, Wencw, bencw, T);
    build_P<<<32768, 128, 0, stream>>>(T, x0, Wencb, bencb, P);
    recur<<<64, 512, kRecurLds, stream>>>(Wencw, bencw, bdecw, bdecb, Wdecb,
                                          WdG, P, mh, flags);
    loss_kernel<<<1024, 256, 0, stream>>>(mh, decwY, decb, x0, out);
}